// Round 1
// baseline (11.230 us; speedup 1.0000x reference)
//
#include <hip/hip_runtime.h>

// CrossCompressUnit, algebraically collapsed:
//   v_out[b,:] = v[b,:]*dot(e[b],w_vv) + e[b,:]*dot(v[b],w_ev) + b_vv
//   e_out[b,:] = v[b,:]*dot(e[b],w_ve) + e[b,:]*dot(v[b],w_ee) + b_ee
// B=8192, D=128. Memory-bound: 16 MiB traffic total.

#define NROWS 8192
#define DIM   128

__global__ __launch_bounds__(256) void ccu_kernel(
    const float* __restrict__ v, const float* __restrict__ e,
    const float* __restrict__ w_vv, const float* __restrict__ b_vv,
    const float* __restrict__ w_ev, const float* __restrict__ w_ve,
    const float* __restrict__ w_ee, const float* __restrict__ b_ee,
    float* __restrict__ out)
{
    const int lane = threadIdx.x & 63;       // wave = 64 on CDNA
    const int wave = threadIdx.x >> 6;       // 4 waves/block
    const int row  = blockIdx.x * 4 + wave;  // one row per wave
    if (row >= NROWS) return;

    const int col2 = lane * 2;               // each lane owns 2 columns

    const float2 vv  = *reinterpret_cast<const float2*>(v + row * DIM + col2);
    const float2 ev  = *reinterpret_cast<const float2*>(e + row * DIM + col2);
    const float2 wvv = *reinterpret_cast<const float2*>(w_vv + col2);
    const float2 wev = *reinterpret_cast<const float2*>(w_ev + col2);
    const float2 wve = *reinterpret_cast<const float2*>(w_ve + col2);
    const float2 wee = *reinterpret_cast<const float2*>(w_ee + col2);

    // per-lane partials of the 4 dot products
    float p0 = ev.x * wvv.x + ev.y * wvv.y;  // dot(e, w_vv)
    float p1 = vv.x * wev.x + vv.y * wev.y;  // dot(v, w_ev)
    float p2 = ev.x * wve.x + ev.y * wve.y;  // dot(e, w_ve)
    float p3 = vv.x * wee.x + vv.y * wee.y;  // dot(v, w_ee)

    // 64-lane butterfly reduction (6 steps), all 4 values
    #pragma unroll
    for (int off = 32; off >= 1; off >>= 1) {
        p0 += __shfl_xor(p0, off, 64);
        p1 += __shfl_xor(p1, off, 64);
        p2 += __shfl_xor(p2, off, 64);
        p3 += __shfl_xor(p3, off, 64);
    }

    const float bvv = b_vv[0];
    const float bee = b_ee[0];

    float2 vo, eo;
    vo.x = vv.x * p0 + ev.x * p1 + bvv;
    vo.y = vv.y * p0 + ev.y * p1 + bvv;
    eo.x = vv.x * p2 + ev.x * p3 + bee;
    eo.y = vv.y * p2 + ev.y * p3 + bee;

    *reinterpret_cast<float2*>(out + row * DIM + col2) = vo;
    *reinterpret_cast<float2*>(out + (size_t)NROWS * DIM + row * DIM + col2) = eo;
}

extern "C" void kernel_launch(void* const* d_in, const int* in_sizes, int n_in,
                              void* d_out, int out_size, void* d_ws, size_t ws_size,
                              hipStream_t stream) {
    const float* v    = (const float*)d_in[0];
    const float* e    = (const float*)d_in[1];
    const float* w_vv = (const float*)d_in[2];
    const float* b_vv = (const float*)d_in[3];
    const float* w_ev = (const float*)d_in[4];
    const float* w_ve = (const float*)d_in[5];
    const float* w_ee = (const float*)d_in[6];
    const float* b_ee = (const float*)d_in[7];
    float* out = (float*)d_out;

    const int rows_per_block = 4;                   // 4 waves * 1 row each
    const int grid = NROWS / rows_per_block;        // 2048 blocks
    ccu_kernel<<<grid, 256, 0, stream>>>(v, e, w_vv, b_vv, w_ev, w_ve, w_ee, b_ee, out);
}

// Round 2
// 10.272 us; speedup vs baseline: 1.0933x; 1.0933x over previous
//
#include <hip/hip_runtime.h>

// CrossCompressUnit, algebraically collapsed:
//   v_out[b,:] = v[b,:]*dot(e[b],w_vv) + e[b,:]*dot(v[b],w_ev) + b_vv
//   e_out[b,:] = v[b,:]*dot(e[b],w_ve) + e[b,:]*dot(v[b],w_ee) + b_ee
// B=8192, D=128. Memory-bound: ~16.8 MB total traffic.
// R2: float4 per lane (16 B coalescing sweet spot), 2 rows per wave
// (lanes 0-31 row A, 32-63 row B), 5-step half-wave butterfly, nt stores.

#define NROWS 8192
#define DIM   128

typedef float floatx4 __attribute__((ext_vector_type(4)));

__global__ __launch_bounds__(256) void ccu_kernel(
    const float* __restrict__ v, const float* __restrict__ e,
    const float* __restrict__ w_vv, const float* __restrict__ b_vv,
    const float* __restrict__ w_ev, const float* __restrict__ w_ve,
    const float* __restrict__ w_ee, const float* __restrict__ b_ee,
    float* __restrict__ out)
{
    const int lane = threadIdx.x & 63;     // wave = 64 on CDNA
    const int wave = threadIdx.x >> 6;     // 4 waves/block
    const int half = lane >> 5;            // 0: row A, 1: row B
    const int l32  = lane & 31;

    const int rp  = blockIdx.x * 4 + wave; // row-pair index [0, 4096)
    const int row = rp * 2 + half;
    const int col = l32 * 4;               // each lane owns 4 columns

    const floatx4 vv  = *reinterpret_cast<const floatx4*>(v + row * DIM + col);
    const floatx4 ev  = *reinterpret_cast<const floatx4*>(e + row * DIM + col);
    const floatx4 wvv = *reinterpret_cast<const floatx4*>(w_vv + col);
    const floatx4 wev = *reinterpret_cast<const floatx4*>(w_ev + col);
    const floatx4 wve = *reinterpret_cast<const floatx4*>(w_ve + col);
    const floatx4 wee = *reinterpret_cast<const floatx4*>(w_ee + col);

    // per-lane partials of the 4 dot products
    float p0 = ev.x*wvv.x + ev.y*wvv.y + ev.z*wvv.z + ev.w*wvv.w; // dot(e, w_vv)
    float p1 = vv.x*wev.x + vv.y*wev.y + vv.z*wev.z + vv.w*wev.w; // dot(v, w_ev)
    float p2 = ev.x*wve.x + ev.y*wve.y + ev.z*wve.z + ev.w*wve.w; // dot(e, w_ve)
    float p3 = vv.x*wee.x + vv.y*wee.y + vv.z*wee.z + vv.w*wee.w; // dot(v, w_ee)

    // 32-lane butterfly (offsets <32 stay within each half-wave / row)
    #pragma unroll
    for (int off = 16; off >= 1; off >>= 1) {
        p0 += __shfl_xor(p0, off, 64);
        p1 += __shfl_xor(p1, off, 64);
        p2 += __shfl_xor(p2, off, 64);
        p3 += __shfl_xor(p3, off, 64);
    }

    const float bvv = b_vv[0];
    const float bee = b_ee[0];

    floatx4 vo, eo;
    vo.x = vv.x*p0 + ev.x*p1 + bvv;
    vo.y = vv.y*p0 + ev.y*p1 + bvv;
    vo.z = vv.z*p0 + ev.z*p1 + bvv;
    vo.w = vv.w*p0 + ev.w*p1 + bvv;
    eo.x = vv.x*p2 + ev.x*p3 + bee;
    eo.y = vv.y*p2 + ev.y*p3 + bee;
    eo.z = vv.z*p2 + ev.z*p3 + bee;
    eo.w = vv.w*p2 + ev.w*p3 + bee;

    __builtin_nontemporal_store(vo, reinterpret_cast<floatx4*>(out + row * DIM + col));
    __builtin_nontemporal_store(eo, reinterpret_cast<floatx4*>(out + (size_t)NROWS * DIM + row * DIM + col));
}

extern "C" void kernel_launch(void* const* d_in, const int* in_sizes, int n_in,
                              void* d_out, int out_size, void* d_ws, size_t ws_size,
                              hipStream_t stream) {
    const float* v    = (const float*)d_in[0];
    const float* e    = (const float*)d_in[1];
    const float* w_vv = (const float*)d_in[2];
    const float* b_vv = (const float*)d_in[3];
    const float* w_ev = (const float*)d_in[4];
    const float* w_ve = (const float*)d_in[5];
    const float* w_ee = (const float*)d_in[6];
    const float* b_ee = (const float*)d_in[7];
    float* out = (float*)d_out;

    // 4 waves/block, 2 rows/wave -> 8 rows/block -> 1024 blocks
    const int grid = NROWS / 8;
    ccu_kernel<<<grid, 256, 0, stream>>>(v, e, w_vv, b_vv, w_ev, w_ve, w_ee, b_ee, out);
}